// Round 9
// baseline (469.549 us; speedup 1.0000x reference)
//
#include <hip/hip_runtime.h>
#include <cstdint>
#include <cstddef>
#include <math.h>

#define NNODES 30000
#define NEDGES 480000

typedef _Float16 f16x8 __attribute__((ext_vector_type(8)));
typedef float f32x4 __attribute__((ext_vector_type(4)));

constexpr unsigned ENC_NEGINF = 0x007FFFFFu;  // encode(-inf)

__device__ __forceinline__ unsigned enc_f32(float f) {
  unsigned u = __float_as_uint(f);
  return (u & 0x80000000u) ? ~u : (u | 0x80000000u);
}
__device__ __forceinline__ float dec_f32(unsigned e) {
  unsigned u = (e & 0x80000000u) ? (e ^ 0x80000000u) : ~e;
  return __uint_as_float(u);
}
__device__ __forceinline__ _Float16 dec_f16(unsigned e) {
  return (_Float16)((e == ENC_NEGINF) ? 0.0f : dec_f32(e));
}

// Bijective XCD-chunked remap (neutral-cost; kept).
__device__ __forceinline__ int xcd_swz(int orig, int nwg) {
  const int NX = 8;
  int q = nwg / NX, r = nwg % NX;
  int x = orig % NX, i = orig / NX;
  return (x < r ? x * (q + 1) : r * (q + 1) + (x - r) * q) + i;
}

// Barrier that drains only LDS (lgkmcnt), NOT vmcnt.
__device__ __forceinline__ void bar_lgkm() {
  __builtin_amdgcn_sched_barrier(0);
  asm volatile("s_waitcnt lgkmcnt(0)\n\ts_barrier" ::: "memory");
  __builtin_amdgcn_sched_barrier(0);
}

__global__ void fill_u32(unsigned* __restrict__ p, int n, unsigned v) {
  int i = blockIdx.x * 256 + threadIdx.x;
  if (i < n) p[i] = v;
}

__global__ __launch_bounds__(1024) void scan_kernel(const int* __restrict__ deg,
                                                    int* __restrict__ cur) {
  __shared__ int part[1024];
  const int tid = threadIdx.x;
  constexpr int PER = 30;  // 1024*30 = 30720 >= 30000
  int loc[PER];
  int s = 0;
  const int base = tid * PER;
#pragma unroll
  for (int i = 0; i < PER; ++i) {
    int idx = base + i;
    int v = (idx < NNODES) ? deg[idx] : 0;
    loc[i] = s;
    s += v;
  }
  part[tid] = s;
  __syncthreads();
  for (int d = 1; d < 1024; d <<= 1) {
    int t = (tid >= d) ? part[tid - d] : 0;
    __syncthreads();
    part[tid] += t;
    __syncthreads();
  }
  const int excl = part[tid] - s;
#pragma unroll
  for (int i = 0; i < PER; ++i) {
    int idx = base + i;
    if (idx < NNODES) cur[idx] = excl + loc[i];
  }
}

// Pack (dst<<16)|src — both < 30000 < 65536.
__global__ void scatter_kernel(const int* __restrict__ eidx, int* __restrict__ cur,
                               unsigned* __restrict__ sedge) {
  int e = blockIdx.x * 256 + threadIdx.x;
  if (e < NEDGES) {
    int s = eidx[e], d = eidx[NEDGES + e];
    int pos = atomicAdd(&cur[d], 1);
    sedge[pos] = ((unsigned)d << 16) | (unsigned)s;
  }
}

// ---- Device helpers for the merged prep kernel ----
__device__ __forceinline__ void do_wT(int idx, const float* __restrict__ W,
                                      _Float16* __restrict__ BT, int Kd, int Nd) {
  int k = idx / Nd, n = idx % Nd;
  BT[(size_t)n * Kd + k] = (_Float16)W[idx];
}
__device__ __forceinline__ void do_bfrag(int idx, const float* __restrict__ W,
                                         _Float16* __restrict__ Bf, int Dd) {
  int j = idx & 7;
  int lane = (idx >> 3) & 63;
  int rest = idx >> 9;
  int ntiles = Dd >> 4;
  int ks = rest / ntiles, tile = rest % ntiles;
  int n = tile * 16 + (lane & 15);
  int k = ks * 32 + (lane >> 4) * 8 + j;
  Bf[idx] = (_Float16)W[(size_t)k * Dd + n];
}
__device__ __forceinline__ void do_pqfrag(int idx, const float* __restrict__ W1,
                                          _Float16* __restrict__ Bfd,
                                          _Float16* __restrict__ Bfb, int Kd, int Dd) {
  int j = idx & 7;
  int lane = (idx >> 3) & 63;
  int rest = idx >> 9;
  int ntiles = Dd >> 4;
  int ks = rest / ntiles, tile = rest % ntiles;
  int n = tile * 16 + (lane & 15);
  int k = ks * 32 + (lane >> 4) * 8 + j;
  float top = W1[(size_t)k * Dd + n];
  float bot = W1[(size_t)(Kd + k) * Dd + n];
  Bfd[idx] = (_Float16)(top - bot);
  Bfb[idx] = (_Float16)bot;
}

// Merged setup: agg1 fill + edge histogram + all 7 weight conversions.
__global__ void prep_kernel(
    const int* __restrict__ eidx, int* __restrict__ deg,
    const float* __restrict__ wm1, const float* __restrict__ wm2,
    const float* __restrict__ w1b, const float* __restrict__ w2b,
    const float* __restrict__ w3b, const float* __restrict__ w2a,
    const float* __restrict__ w3a,
    _Float16* __restrict__ wm1h, _Float16* __restrict__ wm2h,
    _Float16* __restrict__ w1f, _Float16* __restrict__ w2f,
    _Float16* __restrict__ w3f, _Float16* __restrict__ w2pd,
    _Float16* __restrict__ w2pb, _Float16* __restrict__ w3pd,
    _Float16* __restrict__ w3pb, unsigned* __restrict__ agg1) {
  int idx = blockIdx.x * 256 + threadIdx.x;
  constexpr int S_FILL = NNODES * 64;
  constexpr int S_HIST = NEDGES;
  constexpr int S_WM1 = 448 * 512;
  constexpr int S_WM2 = 512 * 256;
  constexpr int S_W1F = 64 * 64;
  constexpr int S_W2F = 128 * 128;
  constexpr int S_W3F = 256 * 256;
  constexpr int S_W2PQ = 64 * 128;
  constexpr int S_W3PQ = 128 * 256;
  if (idx < S_FILL) { agg1[idx] = ENC_NEGINF; return; }
  idx -= S_FILL;
  if (idx < S_HIST) { atomicAdd(&deg[eidx[NEDGES + idx]], 1); return; }
  idx -= S_HIST;
  if (idx < S_WM1) { do_wT(idx, wm1, wm1h, 448, 512); return; }
  idx -= S_WM1;
  if (idx < S_WM2) { do_wT(idx, wm2, wm2h, 512, 256); return; }
  idx -= S_WM2;
  if (idx < S_W1F) { do_bfrag(idx, w1b, w1f, 64); return; }
  idx -= S_W1F;
  if (idx < S_W2F) { do_bfrag(idx, w2b, w2f, 128); return; }
  idx -= S_W2F;
  if (idx < S_W3F) { do_bfrag(idx, w3b, w3f, 256); return; }
  idx -= S_W3F;
  if (idx < S_W2PQ) { do_pqfrag(idx, w2a, w2pd, w2pb, 64, 128); return; }
  idx -= S_W2PQ;
  if (idx < S_W3PQ) { do_pqfrag(idx, w3a, w3pd, w3pb, 128, 256); return; }
}

// Layer-1 P/Q (K=3, fp32 VALU — tiny).
template <int K, int D>
__global__ __launch_bounds__(256) void pq_kernel(
    const float* __restrict__ X, int ldx,
    const float* __restrict__ W1, const float* __restrict__ b1,
    _Float16* __restrict__ P, _Float16* __restrict__ Q) {
  constexpr int KT = 16;
  __shared__ float xs[64][KT + 1];
  __shared__ float wt[KT][64];
  __shared__ float wb[KT][64];
  const int tid = threadIdx.x;
  const int row0 = blockIdx.x * 64;
  const int cb0 = blockIdx.y * 64;
  const int cg = tid & 15, rg = tid >> 4;
  const int c0 = cg * 4, r0 = rg * 4;
  float p[4][4] = {}, q[4][4] = {};
  for (int k0 = 0; k0 < K; k0 += KT) {
    const int kt = (K - k0 < KT) ? (K - k0) : KT;
    for (int idx = tid; idx < 64 * KT; idx += 256) {
      int k = idx & (KT - 1), r = idx >> 4;
      if (k < kt) {
        int rr = row0 + r; if (rr >= NNODES) rr = NNODES - 1;
        xs[r][k] = X[(size_t)rr * ldx + k0 + k];
      }
    }
    for (int idx = tid; idx < KT * 64; idx += 256) {
      int k = idx >> 6, c = idx & 63;
      if (k < kt) {
        wt[k][c] = W1[(size_t)(k0 + k) * D + cb0 + c];
        wb[k][c] = W1[(size_t)(K + k0 + k) * D + cb0 + c];
      }
    }
    __syncthreads();
    for (int kk = 0; kk < kt; ++kk) {
      float xv[4];
#pragma unroll
      for (int i = 0; i < 4; ++i) xv[i] = xs[r0 + i][kk];
      const float4 wtv = *(const float4*)&wt[kk][c0];
      const float4 wbv = *(const float4*)&wb[kk][c0];
      float dv[4] = {wtv.x - wbv.x, wtv.y - wbv.y, wtv.z - wbv.z, wtv.w - wbv.w};
      float bv[4] = {wbv.x, wbv.y, wbv.z, wbv.w};
#pragma unroll
      for (int i = 0; i < 4; ++i) {
#pragma unroll
        for (int j = 0; j < 4; ++j) {
          p[i][j] = fmaf(xv[i], dv[j], p[i][j]);
          q[i][j] = fmaf(xv[i], bv[j], q[i][j]);
        }
      }
    }
    __syncthreads();
  }
  float b1v[4];
#pragma unroll
  for (int j = 0; j < 4; ++j) b1v[j] = b1[cb0 + c0 + j];
#pragma unroll
  for (int i = 0; i < 4; ++i) {
    int rr = row0 + r0 + i;
    if (rr < NNODES) {
      union { _Float16 h[4]; float2 f2; } up, uq;
#pragma unroll
      for (int j = 0; j < 4; ++j) {
        up.h[j] = (_Float16)(p[i][j] + b1v[j]);
        uq.h[j] = (_Float16)q[i][j];
      }
      *(float2*)&P[(size_t)rr * D + cb0 + c0] = up.f2;
      *(float2*)&Q[(size_t)rr * D + cb0 + c0] = uq.f2;
    }
  }
}

// MFMA P/Q for layers 2/3 with fused decode of the previous layer's agg.
template <int K, int D>
__global__ __launch_bounds__(256) void pq_mfma(
    const unsigned* __restrict__ aggIn,
    const _Float16* __restrict__ Bfd, const _Float16* __restrict__ Bfb,
    const float* __restrict__ b1,
    _Float16* __restrict__ P, _Float16* __restrict__ Q) {
  constexpr int SA = K + 8;
  constexpr int NSTEP = K / 32;
  constexpr int NTILES = D / 16;
  constexpr int CH = K / 8;
  __shared__ __align__(16) _Float16 As[64 * SA];
  const int tid = threadIdx.x;
  const int wave = tid >> 6, lane = tid & 63;
  const int l16 = lane & 15, quad = lane >> 4;
  const int row0 = blockIdx.x * 64;
  const int cb0 = blockIdx.y * 128;
  for (int idx = tid; idx < 64 * CH; idx += 256) {
    int r = idx / CH, cc = idx % CH;
    int rr = row0 + r; if (rr >= NNODES) rr = NNODES - 1;
    const unsigned* ap = aggIn + (size_t)rr * K + cc * 8;
    f16x8 h;
#pragma unroll
    for (int j = 0; j < 8; ++j) h[j] = dec_f16(ap[j]);
    *(f16x8*)&As[r * SA + cc * 8] = h;
  }
  bar_lgkm();
  f32x4 accP[4][2] = {}, accQ[4][2] = {};
  const int tbase = cb0 / 16 + wave * 2;
#pragma unroll
  for (int ks = 0; ks < NSTEP; ++ks) {
    f16x8 af[4], bd[2], bb[2];
#pragma unroll
    for (int nt = 0; nt < 2; ++nt) {
      size_t off = (((size_t)ks * NTILES + tbase + nt) * 64 + lane) * 8;
      bd[nt] = *(const f16x8*)(Bfd + off);
      bb[nt] = *(const f16x8*)(Bfb + off);
    }
#pragma unroll
    for (int mt = 0; mt < 4; ++mt)
      af[mt] = *(const f16x8*)&As[(mt * 16 + l16) * SA + ks * 32 + quad * 8];
#pragma unroll
    for (int mt = 0; mt < 4; ++mt)
#pragma unroll
      for (int nt = 0; nt < 2; ++nt) {
        accP[mt][nt] = __builtin_amdgcn_mfma_f32_16x16x32_f16(af[mt], bd[nt], accP[mt][nt], 0, 0, 0);
        accQ[mt][nt] = __builtin_amdgcn_mfma_f32_16x16x32_f16(af[mt], bb[nt], accQ[mt][nt], 0, 0, 0);
      }
  }
#pragma unroll
  for (int nt = 0; nt < 2; ++nt) {
    int n = cb0 + wave * 32 + nt * 16 + l16;
    float bv = b1[n];
#pragma unroll
    for (int mt = 0; mt < 4; ++mt) {
#pragma unroll
      for (int r = 0; r < 4; ++r) {
        int m = row0 + mt * 16 + quad * 4 + r;
        if (m < NNODES) {
          P[(size_t)m * D + n] = (_Float16)(accP[mt][nt][r] + bv);
          Q[(size_t)m * D + n] = (_Float16)accQ[mt][nt][r];
        }
      }
    }
  }
}

// MFMA edge kernel (dst-sorted edges), 64 edges x full D per block —
// SOFTWARE-PIPELINED: gather t-iteration t covers exactly k in
// [32t, 32t+32), the K-slice GEMM step ks=t consumes. Per ks: issue B
// frags for ks; relu+ds_write gather slot ks (loads issued 2 iters ago);
// issue gather loads for ks+2; lgkm barrier; ds_read af; MFMA. Gather
// latency hides under the previous iterations' GEMM. Register-neutral:
// dropped bnext double-buffer (-16 VGPR) pays for the depth-2 gather
// queue (+16 VGPR) — stays at the 64 VGPR + 64 AGPR / 4-wave boundary.
// Inter-wave LDS hazard: max skew is write(ks+1) vs read(ks) — disjoint.
// IW > 0: also initializes the NEXT layer's disjoint agg buffer.
template <int D, int IW>
__global__ __launch_bounds__(256, (D == 256) ? 4 : ((D == 128) ? 5 : 6)) void edge_mfma(
    const unsigned* __restrict__ sedge,
    const _Float16* __restrict__ P, const _Float16* __restrict__ Q,
    const _Float16* __restrict__ Bf,
    const float* __restrict__ b2,
    unsigned* __restrict__ agg, unsigned* __restrict__ aggNext) {
  constexpr int BE = 64;
  constexpr int MT = 4;
  constexpr int NT = D / 64;
  constexpr int NTILES = D / 16;
  constexpr int NSTEP = D / 32;
  constexpr int SL = (BE * D) / 256;
  __shared__ __align__(16) char smem[BE * D * 2];

  const int tid = threadIdx.x;
  const int wave = tid >> 6, lane = tid & 63;
  const int l16 = lane & 15, quad = lane >> 4;
  const int ebase = xcd_swz(blockIdx.x, gridDim.x) * BE;

  if (IW > 0) {
    uint4 f; f.x = f.y = f.z = f.w = ENC_NEGINF;
    for (int i = tid; i < IW / 4; i += 256)
      *(uint4*)&aggNext[(size_t)blockIdx.x * IW + i * 4] = f;
  }

  // ---- Gather addressing + depth-2 rolling prefetch (slots 0/1)
  const int e = tid >> 2, qd = tid & 3;
  unsigned pk = sedge[ebase + e];
  const _Float16* Pr = P + (size_t)(pk >> 16) * D;
  const _Float16* Qr = Q + (size_t)(pk & 0xFFFFu) * D;
  f16x8 pv0 = *(const f16x8*)(Pr + qd * 8);
  f16x8 qv0 = *(const f16x8*)(Qr + qd * 8);
  f16x8 pv1 = *(const f16x8*)(Pr + (qd + 4) * 8);
  f16x8 qv1 = *(const f16x8*)(Qr + (qd + 4) * 8);

  const _Float16* BfW = Bf + ((size_t)(wave * NT) * 64 + lane) * 8;
  f32x4 acc[MT][NT] = {};
#pragma unroll
  for (int ks = 0; ks < NSTEP; ++ks) {
    // B fragments for this ks (L2-hot; hidden under write+barrier)
    f16x8 bf[NT];
#pragma unroll
    for (int nt = 0; nt < NT; ++nt)
      bf[nt] = *(const f16x8*)(BfW + ((size_t)ks * NTILES + nt) * 512);
    // relu + ds_write gather slot ks (waits its 2 loads via data dep)
    {
      f16x8 s = ((ks & 1) ? pv1 : pv0) + ((ks & 1) ? qv1 : qv0);
#pragma unroll
      for (int j = 0; j < 8; ++j) s[j] = (s[j] > (_Float16)0) ? s[j] : (_Float16)0;
      int k = qd * 8 + ks * 32;
      *(f16x8*)(smem + (((e * D + k) * 2) ^ ((e & 7) << 4))) = s;
    }
    // issue gather loads for ks+2 into the slot just freed
    if (ks + 2 < NSTEP) {
      if (ks & 1) {
        pv1 = *(const f16x8*)(Pr + (qd + 4 * (ks + 2)) * 8);
        qv1 = *(const f16x8*)(Qr + (qd + 4 * (ks + 2)) * 8);
      } else {
        pv0 = *(const f16x8*)(Pr + (qd + 4 * (ks + 2)) * 8);
        qv0 = *(const f16x8*)(Qr + (qd + 4 * (ks + 2)) * 8);
      }
    }
    bar_lgkm();  // region ks written by all waves; loads keep flying
    f16x8 af[MT];
#pragma unroll
    for (int mt = 0; mt < MT; ++mt) {
      int r = mt * 16 + l16;
      af[mt] = *(const f16x8*)(smem + (((r * D + ks * 32 + quad * 8) * 2) ^ ((r & 7) << 4)));
    }
    __builtin_amdgcn_s_setprio(1);
#pragma unroll
    for (int mt = 0; mt < MT; ++mt)
#pragma unroll
      for (int nt = 0; nt < NT; ++nt)
        acc[mt][nt] = __builtin_amdgcn_mfma_f32_16x16x32_f16(af[mt], bf[nt], acc[mt][nt], 0, 0, 0);
    __builtin_amdgcn_s_setprio(0);
  }
  bar_lgkm();  // all GEMM A-reads done -> safe to overlay ybuf
  // ---- Phase C1: +bias, f16, into ybuf[c][e]
#pragma unroll
  for (int nt = 0; nt < NT; ++nt) {
    int c = wave * NT * 16 + nt * 16 + l16;
    float bias = b2[c];
#pragma unroll
    for (int mt = 0; mt < MT; ++mt) {
      int e0 = mt * 16 + quad * 4;
      union { _Float16 h[4]; uint2 u; } w;
#pragma unroll
      for (int r = 0; r < 4; ++r) w.h[r] = (_Float16)(acc[mt][nt][r] + bias);
      *(uint2*)(smem + (((c * BE + e0) * 2) ^ ((c & 7) << 4))) = w.u;
    }
  }
  bar_lgkm();
  // ---- Phase C2: segmented max; chunk fast-path; scalar run logic.
  {
    const int c = tid & (D - 1);
    const int g = tid / D;
    const int es = g * SL;
    _Float16 run = (_Float16)(-INFINITY);
    int pd = __builtin_amdgcn_readfirstlane((int)(sedge[ebase + es] >> 16));
#pragma unroll
    for (int eo = 0; eo < SL; eo += 8) {
      int d0 = __builtin_amdgcn_readfirstlane((int)(sedge[ebase + es + eo] >> 16));
      int d7 = __builtin_amdgcn_readfirstlane((int)(sedge[ebase + es + eo + 7] >> 16));
      f16x8 yv = *(const f16x8*)(smem + (((c * BE + es + eo) * 2) ^ ((c & 7) << 4)));
      if (d0 == pd && d7 == pd) {
        _Float16 m0 = (yv[0] > yv[1]) ? yv[0] : yv[1];
        _Float16 m1 = (yv[2] > yv[3]) ? yv[2] : yv[3];
        _Float16 m2 = (yv[4] > yv[5]) ? yv[4] : yv[5];
        _Float16 m3 = (yv[6] > yv[7]) ? yv[6] : yv[7];
        m0 = (m0 > m1) ? m0 : m1;
        m2 = (m2 > m3) ? m2 : m3;
        m0 = (m0 > m2) ? m0 : m2;
        run = (run > m0) ? run : m0;
      } else {
        int dv[8];
#pragma unroll
        for (int u = 0; u < 8; ++u)
          dv[u] = (int)(sedge[ebase + es + eo + u] >> 16);
#pragma unroll
        for (int u = 0; u < 8; ++u) {
          int d = dv[u];
          if (d != pd) {
            atomicMax(&agg[(size_t)pd * D + c], enc_f32((float)run));
            run = (_Float16)(-INFINITY);
            pd = d;
          }
          _Float16 y = yv[u];
          run = (run > y) ? run : y;
        }
      }
    }
    atomicMax(&agg[(size_t)pd * D + c], enc_f32((float)run));
  }
}

// MFMA MLP GEMM: Y = act(X @ W + b). Block: 64 rows x 128 cols; 4 waves.
// ADEC: the K=448 input is decoded inline from agg1/agg2/agg3.
template <int K, int NTOT, bool RELU, bool ADEC>
__global__ __launch_bounds__(256) void mlp_mfma(
    const _Float16* __restrict__ Xh,
    const unsigned* __restrict__ agg1, const unsigned* __restrict__ agg2,
    const unsigned* __restrict__ agg3,
    const _Float16* __restrict__ BT,
    const float* __restrict__ bias, _Float16* __restrict__ Yv) {
  constexpr int KT = 64;
  constexpr int SA = KT + 8;  // 72
  __shared__ __align__(16) _Float16 As[64 * SA];
  __shared__ __align__(16) _Float16 Bs[128 * SA];
  const int tid = threadIdx.x;
  const int wave = tid >> 6, lane = tid & 63;
  const int l16 = lane & 15, quad = lane >> 4;
  const int row0 = blockIdx.x * 64;
  const int cb0 = blockIdx.y * 128;
  f32x4 acc[4][2] = {};
#pragma unroll
  for (int k0 = 0; k0 < K; k0 += KT) {
    bar_lgkm();
    if (!ADEC) {
      for (int idx = tid; idx < 512; idx += 256) {
        int r = idx >> 3, cc = idx & 7;
        int rr = row0 + r; if (rr >= NNODES) rr = NNODES - 1;
        *(float4*)&As[r * SA + cc * 8] = *(const float4*)&Xh[(size_t)rr * K + k0 + cc * 8];
      }
    } else {
      for (int idx = tid; idx < 512; idx += 256) {
        int r = idx >> 3, cc = idx & 7;
        int rr = row0 + r; if (rr >= NNODES) rr = NNODES - 1;
        const unsigned* ap;
        if (k0 < 64)       ap = agg1 + (size_t)rr * 64 + k0 + cc * 8;
        else if (k0 < 192) ap = agg2 + (size_t)rr * 128 + (k0 - 64) + cc * 8;
        else               ap = agg3 + (size_t)rr * 256 + (k0 - 192) + cc * 8;
        f16x8 h;
#pragma unroll
        for (int j = 0; j < 8; ++j) h[j] = dec_f16(ap[j]);
        *(f16x8*)&As[r * SA + cc * 8] = h;
      }
    }
    for (int idx = tid; idx < 1024; idx += 256) {
      int n = idx >> 3, cc = idx & 7;
      *(float4*)&Bs[n * SA + cc * 8] = *(const float4*)&BT[(size_t)(cb0 + n) * K + k0 + cc * 8];
    }
    bar_lgkm();
#pragma unroll
    for (int kh = 0; kh < 2; ++kh) {
      f16x8 af[4], bf[2];
#pragma unroll
      for (int mt = 0; mt < 4; ++mt)
        af[mt] = *(const f16x8*)&As[(mt * 16 + l16) * SA + kh * 32 + quad * 8];
#pragma unroll
      for (int nt = 0; nt < 2; ++nt)
        bf[nt] = *(const f16x8*)&Bs[(wave * 32 + nt * 16 + l16) * SA + kh * 32 + quad * 8];
#pragma unroll
      for (int mt = 0; mt < 4; ++mt)
#pragma unroll
        for (int nt = 0; nt < 2; ++nt)
          acc[mt][nt] = __builtin_amdgcn_mfma_f32_16x16x32_f16(af[mt], bf[nt], acc[mt][nt], 0, 0, 0);
    }
  }
#pragma unroll
  for (int nt = 0; nt < 2; ++nt) {
    int n = cb0 + wave * 32 + nt * 16 + l16;
    float bv = bias[n];
#pragma unroll
    for (int mt = 0; mt < 4; ++mt) {
#pragma unroll
      for (int r = 0; r < 4; ++r) {
        int m = row0 + mt * 16 + quad * 4 + r;
        if (m < NNODES) {
          float v = acc[mt][nt][r] + bv;
          if (RELU) v = fmaxf(v, 0.0f);
          Yv[(size_t)m * NTOT + n] = (_Float16)v;
        }
      }
    }
  }
}

// Final 256 -> 4 projection (f16 input).
__global__ __launch_bounds__(256) void final_kernel(
    const _Float16* __restrict__ X, const float* __restrict__ W,
    const float* __restrict__ b, float* __restrict__ out) {
  __shared__ float as[64][65];
  __shared__ float ws3[256][4];
  __shared__ float bs[4];
  const int tid = threadIdx.x;
  const int row0 = blockIdx.x * 64;
  for (int idx = tid; idx < 256 * 4; idx += 256) ws3[idx >> 2][idx & 3] = W[idx];
  if (tid < 4) bs[tid] = b[tid];
  const int r = tid >> 2, c = tid & 3;
  float acc = 0.0f;
  for (int k0 = 0; k0 < 256; k0 += 64) {
    __syncthreads();
    for (int idx = tid; idx < 512; idx += 256) {  // 64 rows x 64 cols / 8
      int r2 = idx >> 3, cc = idx & 7;
      int rr = row0 + r2; if (rr >= NNODES) rr = NNODES - 1;
      f16x8 v = *(const f16x8*)&X[(size_t)rr * 256 + k0 + cc * 8];
#pragma unroll
      for (int j = 0; j < 8; ++j) as[r2][cc * 8 + j] = (float)v[j];
    }
    __syncthreads();
#pragma unroll
    for (int kk = 0; kk < 64; ++kk) acc = fmaf(as[r][kk], ws3[k0 + kk][c], acc);
  }
  int rr = row0 + r;
  if (rr < NNODES) out[(size_t)rr * 4 + c] = acc + bs[c];
}

extern "C" void kernel_launch(void* const* d_in, const int* in_sizes, int n_in,
                              void* d_out, int out_size, void* d_ws, size_t ws_size,
                              hipStream_t stream) {
  const float* x = (const float*)d_in[0];
  const int* eidx = (const int*)d_in[1];  // int32
  const float* w1a = (const float*)d_in[3];
  const float* b1a = (const float*)d_in[4];
  const float* w1b = (const float*)d_in[5];
  const float* b1b = (const float*)d_in[6];
  const float* w2a = (const float*)d_in[7];
  const float* b2a = (const float*)d_in[8];
  const float* w2b = (const float*)d_in[9];
  const float* b2b = (const float*)d_in[10];
  const float* w3a = (const float*)d_in[11];
  const float* b3a = (const float*)d_in[12];
  const float* w3b = (const float*)d_in[13];
  const float* b3b = (const float*)d_in[14];
  const float* wm1 = (const float*)d_in[15];
  const float* bm1 = (const float*)d_in[16];
  const float* wm2 = (const float*)d_in[17];
  const float* bm2 = (const float*)d_in[18];
  const float* wm3 = (const float*)d_in[19];
  const float* bm3 = (const float*)d_in[20];
  float* out = (float*)d_out;

  // Workspace (halves unless noted), ~87 MB — exact R6 layout:
  // Ph[N*256] | Qh[N*256] | agg1[N*64 u32] | agg2[N*128 u32] | agg3[N*256 u32]
  //   | sedge[E u32] | wm1h | w2pd/w2pb | w3pd/w3pb
  // Overlays: deg/cur on Ph (dead before pq1); mh1h (f16 N*512) on Ph+Qh
  // (dead after edge3); mh2h (f16 N*256) on agg1+agg2 (dead after mlp1's
  // reads). Edge frag weights + wm2h in d_out (434 KB, read before final).
  _Float16* wsh = (_Float16*)d_ws;
  _Float16* Ph = wsh;
  _Float16* Qh = Ph + (size_t)NNODES * 256;
  unsigned* agg1 = (unsigned*)(Qh + (size_t)NNODES * 256);
  unsigned* agg2 = agg1 + (size_t)NNODES * 64;
  unsigned* agg3 = agg2 + (size_t)NNODES * 128;
  unsigned* sedge = agg3 + (size_t)NNODES * 256;
  _Float16* wm1h = (_Float16*)(sedge + NEDGES);
  _Float16* w2pd = wm1h + 448 * 512;
  _Float16* w2pb = w2pd + 64 * 128;
  _Float16* w3pd = w2pb + 64 * 128;
  _Float16* w3pb = w3pd + 128 * 256;
  int* deg = (int*)Ph;
  int* cur = deg + NNODES;
  _Float16* mh1h = Ph;                     // N*512 halves over Ph+Qh
  _Float16* mh2h = (_Float16*)agg1;        // N*256 halves over agg1+agg2
  _Float16* w1f = (_Float16*)d_out;        // 64*64
  _Float16* w2f = w1f + 4096;              // 128*128
  _Float16* w3f = w2f + 16384;             // 256*256
  _Float16* wm2h = w3f + 65536;            // 256*512 -> total 434 KB

  const int ROWB64 = (NNODES + 63) / 64;     // 469
  const int EB = (NEDGES + 255) / 256;

  // ---- CSR + setup
  fill_u32<<<(NNODES + 255) / 256, 256, 0, stream>>>((unsigned*)deg, NNODES, 0u);
  constexpr int PREP_TOTAL = NNODES * 64 + NEDGES + 448 * 512 + 512 * 256 +
                             64 * 64 + 128 * 128 + 256 * 256 + 64 * 128 + 128 * 256;
  prep_kernel<<<(PREP_TOTAL + 255) / 256, 256, 0, stream>>>(
      eidx, deg, wm1, wm2, w1b, w2b, w3b, w2a, w3a,
      wm1h, wm2h, w1f, w2f, w3f, w2pd, w2pb, w3pd, w3pb, agg1);
  scan_kernel<<<1, 1024, 0, stream>>>(deg, cur);
  scatter_kernel<<<EB, 256, 0, stream>>>(eidx, cur, sedge);

  // ---- EdgeConv 1: C=3 -> 64 (inits agg2: 7500*512 = N*128)
  pq_kernel<3, 64><<<dim3(ROWB64, 1), 256, 0, stream>>>(x, 3, w1a, b1a, Ph, Qh);
  edge_mfma<64, 512><<<NEDGES / 64, 256, 0, stream>>>(sedge, Ph, Qh, w1f, b1b, agg1, agg2);
  // ---- EdgeConv 2: C=64 -> 128 (inits agg3: 7500*1024 = N*256)
  pq_mfma<64, 128><<<dim3(ROWB64, 1), 256, 0, stream>>>(agg1, w2pd, w2pb, b2a, Ph, Qh);
  edge_mfma<128, 1024><<<NEDGES / 64, 256, 0, stream>>>(sedge, Ph, Qh, w2f, b2b, agg2, agg3);
  // ---- EdgeConv 3: C=128 -> 256
  pq_mfma<128, 256><<<dim3(ROWB64, 2), 256, 0, stream>>>(agg2, w3pd, w3pb, b3a, Ph, Qh);
  edge_mfma<256, 0><<<NEDGES / 64, 256, 0, stream>>>(sedge, Ph, Qh, w3f, b3b, agg3, nullptr);
  // ---- MLP head (exact R6): mlp1 inline-decode; mlp2 separate; final
  mlp_mfma<448, 512, true, true><<<dim3(ROWB64, 4), 256, 0, stream>>>(
      nullptr, agg1, agg2, agg3, wm1h, bm1, mh1h);
  mlp_mfma<512, 256, true, false><<<dim3(ROWB64, 2), 256, 0, stream>>>(
      mh1h, nullptr, nullptr, nullptr, wm2h, bm2, mh2h);
  final_kernel<<<ROWB64, 256, 0, stream>>>(mh2h, wm3, bm3, out);
}

// Round 10
// 455.080 us; speedup vs baseline: 1.0318x; 1.0318x over previous
//
#include <hip/hip_runtime.h>
#include <cstdint>
#include <cstddef>
#include <math.h>

#define NNODES 30000
#define NEDGES 480000

typedef _Float16 f16x8 __attribute__((ext_vector_type(8)));
typedef float f32x4 __attribute__((ext_vector_type(4)));

constexpr unsigned ENC_NEGINF = 0x007FFFFFu;  // encode(-inf)

__device__ __forceinline__ unsigned enc_f32(float f) {
  unsigned u = __float_as_uint(f);
  return (u & 0x80000000u) ? ~u : (u | 0x80000000u);
}
__device__ __forceinline__ float dec_f32(unsigned e) {
  unsigned u = (e & 0x80000000u) ? (e ^ 0x80000000u) : ~e;
  return __uint_as_float(u);
}
__device__ __forceinline__ _Float16 dec_f16(unsigned e) {
  return (_Float16)((e == ENC_NEGINF) ? 0.0f : dec_f32(e));
}

// Bijective XCD-chunked remap (neutral-cost; kept).
__device__ __forceinline__ int xcd_swz(int orig, int nwg) {
  const int NX = 8;
  int q = nwg / NX, r = nwg % NX;
  int x = orig % NX, i = orig / NX;
  return (x < r ? x * (q + 1) : r * (q + 1) + (x - r) * q) + i;
}

// Barrier that drains only LDS (lgkmcnt), NOT vmcnt: in-flight gather loads
// and fire-and-forget atomicMax traffic keep flying across it.
__device__ __forceinline__ void bar_lgkm() {
  __builtin_amdgcn_sched_barrier(0);
  asm volatile("s_waitcnt lgkmcnt(0)\n\ts_barrier" ::: "memory");
  __builtin_amdgcn_sched_barrier(0);
}

__global__ void fill_u32(unsigned* __restrict__ p, int n, unsigned v) {
  int i = blockIdx.x * 256 + threadIdx.x;
  if (i < n) p[i] = v;
}

__global__ __launch_bounds__(1024) void scan_kernel(const int* __restrict__ deg,
                                                    int* __restrict__ cur) {
  __shared__ int part[1024];
  const int tid = threadIdx.x;
  constexpr int PER = 30;  // 1024*30 = 30720 >= 30000
  int loc[PER];
  int s = 0;
  const int base = tid * PER;
#pragma unroll
  for (int i = 0; i < PER; ++i) {
    int idx = base + i;
    int v = (idx < NNODES) ? deg[idx] : 0;
    loc[i] = s;
    s += v;
  }
  part[tid] = s;
  __syncthreads();
  for (int d = 1; d < 1024; d <<= 1) {
    int t = (tid >= d) ? part[tid - d] : 0;
    __syncthreads();
    part[tid] += t;
    __syncthreads();
  }
  const int excl = part[tid] - s;
#pragma unroll
  for (int i = 0; i < PER; ++i) {
    int idx = base + i;
    if (idx < NNODES) cur[idx] = excl + loc[i];
  }
}

// Pack (dst<<16)|src — both < 30000 < 65536.
__global__ void scatter_kernel(const int* __restrict__ eidx, int* __restrict__ cur,
                               unsigned* __restrict__ sedge) {
  int e = blockIdx.x * 256 + threadIdx.x;
  if (e < NEDGES) {
    int s = eidx[e], d = eidx[NEDGES + e];
    int pos = atomicAdd(&cur[d], 1);
    sedge[pos] = ((unsigned)d << 16) | (unsigned)s;
  }
}

// ---- Device helpers for the merged prep kernel ----
__device__ __forceinline__ void do_wT(int idx, const float* __restrict__ W,
                                      _Float16* __restrict__ BT, int Kd, int Nd) {
  int k = idx / Nd, n = idx % Nd;
  BT[(size_t)n * Kd + k] = (_Float16)W[idx];
}
__device__ __forceinline__ void do_bfrag(int idx, const float* __restrict__ W,
                                         _Float16* __restrict__ Bf, int Dd) {
  int j = idx & 7;
  int lane = (idx >> 3) & 63;
  int rest = idx >> 9;
  int ntiles = Dd >> 4;
  int ks = rest / ntiles, tile = rest % ntiles;
  int n = tile * 16 + (lane & 15);
  int k = ks * 32 + (lane >> 4) * 8 + j;
  Bf[idx] = (_Float16)W[(size_t)k * Dd + n];
}
__device__ __forceinline__ void do_pqfrag(int idx, const float* __restrict__ W1,
                                          _Float16* __restrict__ Bfd,
                                          _Float16* __restrict__ Bfb, int Kd, int Dd) {
  int j = idx & 7;
  int lane = (idx >> 3) & 63;
  int rest = idx >> 9;
  int ntiles = Dd >> 4;
  int ks = rest / ntiles, tile = rest % ntiles;
  int n = tile * 16 + (lane & 15);
  int k = ks * 32 + (lane >> 4) * 8 + j;
  float top = W1[(size_t)k * Dd + n];
  float bot = W1[(size_t)(Kd + k) * Dd + n];
  Bfd[idx] = (_Float16)(top - bot);
  Bfb[idx] = (_Float16)bot;
}

// Merged setup: agg1 fill + edge histogram + all 7 weight conversions.
__global__ void prep_kernel(
    const int* __restrict__ eidx, int* __restrict__ deg,
    const float* __restrict__ wm1, const float* __restrict__ wm2,
    const float* __restrict__ w1b, const float* __restrict__ w2b,
    const float* __restrict__ w3b, const float* __restrict__ w2a,
    const float* __restrict__ w3a,
    _Float16* __restrict__ wm1h, _Float16* __restrict__ wm2h,
    _Float16* __restrict__ w1f, _Float16* __restrict__ w2f,
    _Float16* __restrict__ w3f, _Float16* __restrict__ w2pd,
    _Float16* __restrict__ w2pb, _Float16* __restrict__ w3pd,
    _Float16* __restrict__ w3pb, unsigned* __restrict__ agg1) {
  int idx = blockIdx.x * 256 + threadIdx.x;
  constexpr int S_FILL = NNODES * 64;
  constexpr int S_HIST = NEDGES;
  constexpr int S_WM1 = 448 * 512;
  constexpr int S_WM2 = 512 * 256;
  constexpr int S_W1F = 64 * 64;
  constexpr int S_W2F = 128 * 128;
  constexpr int S_W3F = 256 * 256;
  constexpr int S_W2PQ = 64 * 128;
  constexpr int S_W3PQ = 128 * 256;
  if (idx < S_FILL) { agg1[idx] = ENC_NEGINF; return; }
  idx -= S_FILL;
  if (idx < S_HIST) { atomicAdd(&deg[eidx[NEDGES + idx]], 1); return; }
  idx -= S_HIST;
  if (idx < S_WM1) { do_wT(idx, wm1, wm1h, 448, 512); return; }
  idx -= S_WM1;
  if (idx < S_WM2) { do_wT(idx, wm2, wm2h, 512, 256); return; }
  idx -= S_WM2;
  if (idx < S_W1F) { do_bfrag(idx, w1b, w1f, 64); return; }
  idx -= S_W1F;
  if (idx < S_W2F) { do_bfrag(idx, w2b, w2f, 128); return; }
  idx -= S_W2F;
  if (idx < S_W3F) { do_bfrag(idx, w3b, w3f, 256); return; }
  idx -= S_W3F;
  if (idx < S_W2PQ) { do_pqfrag(idx, w2a, w2pd, w2pb, 64, 128); return; }
  idx -= S_W2PQ;
  if (idx < S_W3PQ) { do_pqfrag(idx, w3a, w3pd, w3pb, 128, 256); return; }
}

// Layer-1 P/Q (K=3, fp32 VALU — tiny).
template <int K, int D>
__global__ __launch_bounds__(256) void pq_kernel(
    const float* __restrict__ X, int ldx,
    const float* __restrict__ W1, const float* __restrict__ b1,
    _Float16* __restrict__ P, _Float16* __restrict__ Q) {
  constexpr int KT = 16;
  __shared__ float xs[64][KT + 1];
  __shared__ float wt[KT][64];
  __shared__ float wb[KT][64];
  const int tid = threadIdx.x;
  const int row0 = blockIdx.x * 64;
  const int cb0 = blockIdx.y * 64;
  const int cg = tid & 15, rg = tid >> 4;
  const int c0 = cg * 4, r0 = rg * 4;
  float p[4][4] = {}, q[4][4] = {};
  for (int k0 = 0; k0 < K; k0 += KT) {
    const int kt = (K - k0 < KT) ? (K - k0) : KT;
    for (int idx = tid; idx < 64 * KT; idx += 256) {
      int k = idx & (KT - 1), r = idx >> 4;
      if (k < kt) {
        int rr = row0 + r; if (rr >= NNODES) rr = NNODES - 1;
        xs[r][k] = X[(size_t)rr * ldx + k0 + k];
      }
    }
    for (int idx = tid; idx < KT * 64; idx += 256) {
      int k = idx >> 6, c = idx & 63;
      if (k < kt) {
        wt[k][c] = W1[(size_t)(k0 + k) * D + cb0 + c];
        wb[k][c] = W1[(size_t)(K + k0 + k) * D + cb0 + c];
      }
    }
    __syncthreads();
    for (int kk = 0; kk < kt; ++kk) {
      float xv[4];
#pragma unroll
      for (int i = 0; i < 4; ++i) xv[i] = xs[r0 + i][kk];
      const float4 wtv = *(const float4*)&wt[kk][c0];
      const float4 wbv = *(const float4*)&wb[kk][c0];
      float dv[4] = {wtv.x - wbv.x, wtv.y - wbv.y, wtv.z - wbv.z, wtv.w - wbv.w};
      float bv[4] = {wbv.x, wbv.y, wbv.z, wbv.w};
#pragma unroll
      for (int i = 0; i < 4; ++i) {
#pragma unroll
        for (int j = 0; j < 4; ++j) {
          p[i][j] = fmaf(xv[i], dv[j], p[i][j]);
          q[i][j] = fmaf(xv[i], bv[j], q[i][j]);
        }
      }
    }
    __syncthreads();
  }
  float b1v[4];
#pragma unroll
  for (int j = 0; j < 4; ++j) b1v[j] = b1[cb0 + c0 + j];
#pragma unroll
  for (int i = 0; i < 4; ++i) {
    int rr = row0 + r0 + i;
    if (rr < NNODES) {
      union { _Float16 h[4]; float2 f2; } up, uq;
#pragma unroll
      for (int j = 0; j < 4; ++j) {
        up.h[j] = (_Float16)(p[i][j] + b1v[j]);
        uq.h[j] = (_Float16)q[i][j];
      }
      *(float2*)&P[(size_t)rr * D + cb0 + c0] = up.f2;
      *(float2*)&Q[(size_t)rr * D + cb0 + c0] = uq.f2;
    }
  }
}

// MFMA P/Q for layers 2/3 with fused decode of the previous layer's agg.
template <int K, int D>
__global__ __launch_bounds__(256) void pq_mfma(
    const unsigned* __restrict__ aggIn,
    const _Float16* __restrict__ Bfd, const _Float16* __restrict__ Bfb,
    const float* __restrict__ b1,
    _Float16* __restrict__ P, _Float16* __restrict__ Q) {
  constexpr int SA = K + 8;
  constexpr int NSTEP = K / 32;
  constexpr int NTILES = D / 16;
  constexpr int CH = K / 8;
  __shared__ __align__(16) _Float16 As[64 * SA];
  const int tid = threadIdx.x;
  const int wave = tid >> 6, lane = tid & 63;
  const int l16 = lane & 15, quad = lane >> 4;
  const int row0 = blockIdx.x * 64;
  const int cb0 = blockIdx.y * 128;
  for (int idx = tid; idx < 64 * CH; idx += 256) {
    int r = idx / CH, cc = idx % CH;
    int rr = row0 + r; if (rr >= NNODES) rr = NNODES - 1;
    const unsigned* ap = aggIn + (size_t)rr * K + cc * 8;
    f16x8 h;
#pragma unroll
    for (int j = 0; j < 8; ++j) h[j] = dec_f16(ap[j]);
    *(f16x8*)&As[r * SA + cc * 8] = h;
  }
  bar_lgkm();
  f32x4 accP[4][2] = {}, accQ[4][2] = {};
  const int tbase = cb0 / 16 + wave * 2;
#pragma unroll
  for (int ks = 0; ks < NSTEP; ++ks) {
    f16x8 af[4], bd[2], bb[2];
#pragma unroll
    for (int nt = 0; nt < 2; ++nt) {
      size_t off = (((size_t)ks * NTILES + tbase + nt) * 64 + lane) * 8;
      bd[nt] = *(const f16x8*)(Bfd + off);
      bb[nt] = *(const f16x8*)(Bfb + off);
    }
#pragma unroll
    for (int mt = 0; mt < 4; ++mt)
      af[mt] = *(const f16x8*)&As[(mt * 16 + l16) * SA + ks * 32 + quad * 8];
#pragma unroll
    for (int mt = 0; mt < 4; ++mt)
#pragma unroll
      for (int nt = 0; nt < 2; ++nt) {
        accP[mt][nt] = __builtin_amdgcn_mfma_f32_16x16x32_f16(af[mt], bd[nt], accP[mt][nt], 0, 0, 0);
        accQ[mt][nt] = __builtin_amdgcn_mfma_f32_16x16x32_f16(af[mt], bb[nt], accQ[mt][nt], 0, 0, 0);
      }
  }
#pragma unroll
  for (int nt = 0; nt < 2; ++nt) {
    int n = cb0 + wave * 32 + nt * 16 + l16;
    float bv = b1[n];
#pragma unroll
    for (int mt = 0; mt < 4; ++mt) {
#pragma unroll
      for (int r = 0; r < 4; ++r) {
        int m = row0 + mt * 16 + quad * 4 + r;
        if (m < NNODES) {
          P[(size_t)m * D + n] = (_Float16)(accP[mt][nt][r] + bv);
          Q[(size_t)m * D + n] = (_Float16)accQ[mt][nt][r];
        }
      }
    }
  }
}

// MFMA edge kernel (dst-sorted edges), 64 edges x full D per block — the
// converged R6 structure. Falsified alternatives (counter evidence):
// N-split (2x gather FETCH), BE=128 (occupancy step), per-ks pipelining
// (barrier convoy, MfmaUtil -1.6), XCD swizzle (FETCH unmoved — kept only
// as neutral). IW > 0: also inits the NEXT layer's disjoint agg buffer.
template <int D, int IW>
__global__ __launch_bounds__(256, (D == 256) ? 4 : ((D == 128) ? 5 : 6)) void edge_mfma(
    const unsigned* __restrict__ sedge,
    const _Float16* __restrict__ P, const _Float16* __restrict__ Q,
    const _Float16* __restrict__ Bf,
    const float* __restrict__ b2,
    unsigned* __restrict__ agg, unsigned* __restrict__ aggNext) {
  constexpr int BE = 64;
  constexpr int MT = 4;
  constexpr int NT = D / 64;
  constexpr int NTILES = D / 16;
  constexpr int NSTEP = D / 32;
  constexpr int SL = (BE * D) / 256;
  __shared__ __align__(16) char smem[BE * D * 2];

  const int tid = threadIdx.x;
  const int wave = tid >> 6, lane = tid & 63;
  const int l16 = lane & 15, quad = lane >> 4;
  const int ebase = xcd_swz(blockIdx.x, gridDim.x) * BE;

  if (IW > 0) {
    uint4 f; f.x = f.y = f.z = f.w = ENC_NEGINF;
    for (int i = tid; i < IW / 4; i += 256)
      *(uint4*)&aggNext[(size_t)blockIdx.x * IW + i * 4] = f;
  }

  // ---- Prefetch ks=0 B fragments
  const _Float16* BfW = Bf + ((size_t)(wave * NT) * 64 + lane) * 8;
  f16x8 bcur[NT];
#pragma unroll
  for (int nt = 0; nt < NT; ++nt)
    bcur[nt] = *(const f16x8*)(BfW + (size_t)nt * 512);

  // ---- Phase A: t1 = relu(P[dst]+Q[src]) into swizzled Abuf
  {
    const int e = tid >> 2, qd = tid & 3;
    unsigned pk = sedge[ebase + e];
    const _Float16* Pr = P + (size_t)(pk >> 16) * D;
    const _Float16* Qr = Q + (size_t)(pk & 0xFFFFu) * D;
#pragma unroll
    for (int t = 0; t < D / 32; ++t) {
      int k = (qd + 4 * t) * 8;
      f16x8 pv = *(const f16x8*)(Pr + k);
      f16x8 qv = *(const f16x8*)(Qr + k);
      f16x8 s = pv + qv;
#pragma unroll
      for (int j = 0; j < 8; ++j) s[j] = (s[j] > (_Float16)0) ? s[j] : (_Float16)0;
      *(f16x8*)(smem + (((e * D + k) * 2) ^ ((e & 7) << 4))) = s;
    }
  }
  bar_lgkm();
  // ---- Phase B: GEMM, B fragments double-buffered from L2
  f32x4 acc[MT][NT] = {};
#pragma unroll
  for (int ks = 0; ks < NSTEP; ++ks) {
    f16x8 bnext[NT];
    if (ks + 1 < NSTEP) {
#pragma unroll
      for (int nt = 0; nt < NT; ++nt)
        bnext[nt] = *(const f16x8*)(BfW + ((size_t)(ks + 1) * NTILES + nt) * 512);
    }
    f16x8 af[MT];
#pragma unroll
    for (int mt = 0; mt < MT; ++mt) {
      int r = mt * 16 + l16;
      af[mt] = *(const f16x8*)(smem + (((r * D + ks * 32 + quad * 8) * 2) ^ ((r & 7) << 4)));
    }
    __builtin_amdgcn_s_setprio(1);
#pragma unroll
    for (int mt = 0; mt < MT; ++mt)
#pragma unroll
      for (int nt = 0; nt < NT; ++nt)
        acc[mt][nt] = __builtin_amdgcn_mfma_f32_16x16x32_f16(af[mt], bcur[nt], acc[mt][nt], 0, 0, 0);
    __builtin_amdgcn_s_setprio(0);
    if (ks + 1 < NSTEP) {
#pragma unroll
      for (int nt = 0; nt < NT; ++nt) bcur[nt] = bnext[nt];
    }
  }
  bar_lgkm();  // all GEMM A-reads done -> safe to overlay ybuf
  // ---- Phase C1: +bias, f16, into ybuf[c][e]
#pragma unroll
  for (int nt = 0; nt < NT; ++nt) {
    int c = wave * NT * 16 + nt * 16 + l16;
    float bias = b2[c];
#pragma unroll
    for (int mt = 0; mt < MT; ++mt) {
      int e0 = mt * 16 + quad * 4;
      union { _Float16 h[4]; uint2 u; } w;
#pragma unroll
      for (int r = 0; r < 4; ++r) w.h[r] = (_Float16)(acc[mt][nt][r] + bias);
      *(uint2*)(smem + (((c * BE + e0) * 2) ^ ((c & 7) << 4))) = w.u;
    }
  }
  bar_lgkm();
  // ---- Phase C2: segmented max; chunk fast-path; scalar run logic.
  {
    const int c = tid & (D - 1);
    const int g = tid / D;
    const int es = g * SL;
    _Float16 run = (_Float16)(-INFINITY);
    int pd = __builtin_amdgcn_readfirstlane((int)(sedge[ebase + es] >> 16));
#pragma unroll
    for (int eo = 0; eo < SL; eo += 8) {
      int d0 = __builtin_amdgcn_readfirstlane((int)(sedge[ebase + es + eo] >> 16));
      int d7 = __builtin_amdgcn_readfirstlane((int)(sedge[ebase + es + eo + 7] >> 16));
      f16x8 yv = *(const f16x8*)(smem + (((c * BE + es + eo) * 2) ^ ((c & 7) << 4)));
      if (d0 == pd && d7 == pd) {
        _Float16 m0 = (yv[0] > yv[1]) ? yv[0] : yv[1];
        _Float16 m1 = (yv[2] > yv[3]) ? yv[2] : yv[3];
        _Float16 m2 = (yv[4] > yv[5]) ? yv[4] : yv[5];
        _Float16 m3 = (yv[6] > yv[7]) ? yv[6] : yv[7];
        m0 = (m0 > m1) ? m0 : m1;
        m2 = (m2 > m3) ? m2 : m3;
        m0 = (m0 > m2) ? m0 : m2;
        run = (run > m0) ? run : m0;
      } else {
        int dv[8];
#pragma unroll
        for (int u = 0; u < 8; ++u)
          dv[u] = (int)(sedge[ebase + es + eo + u] >> 16);
#pragma unroll
        for (int u = 0; u < 8; ++u) {
          int d = dv[u];
          if (d != pd) {
            atomicMax(&agg[(size_t)pd * D + c], enc_f32((float)run));
            run = (_Float16)(-INFINITY);
            pd = d;
          }
          _Float16 y = yv[u];
          run = (run > y) ? run : y;
        }
      }
    }
    atomicMax(&agg[(size_t)pd * D + c], enc_f32((float)run));
  }
}

// MFMA MLP GEMM: Y = act(X @ W + b). Block: 64 rows x 128 cols; 4 waves.
// ADEC: the K=448 input is decoded inline from agg1/agg2/agg3.
template <int K, int NTOT, bool RELU, bool ADEC>
__global__ __launch_bounds__(256) void mlp_mfma(
    const _Float16* __restrict__ Xh,
    const unsigned* __restrict__ agg1, const unsigned* __restrict__ agg2,
    const unsigned* __restrict__ agg3,
    const _Float16* __restrict__ BT,
    const float* __restrict__ bias, _Float16* __restrict__ Yv) {
  constexpr int KT = 64;
  constexpr int SA = KT + 8;  // 72
  __shared__ __align__(16) _Float16 As[64 * SA];
  __shared__ __align__(16) _Float16 Bs[128 * SA];
  const int tid = threadIdx.x;
  const int wave = tid >> 6, lane = tid & 63;
  const int l16 = lane & 15, quad = lane >> 4;
  const int row0 = blockIdx.x * 64;
  const int cb0 = blockIdx.y * 128;
  f32x4 acc[4][2] = {};
#pragma unroll
  for (int k0 = 0; k0 < K; k0 += KT) {
    bar_lgkm();
    if (!ADEC) {
      for (int idx = tid; idx < 512; idx += 256) {
        int r = idx >> 3, cc = idx & 7;
        int rr = row0 + r; if (rr >= NNODES) rr = NNODES - 1;
        *(float4*)&As[r * SA + cc * 8] = *(const float4*)&Xh[(size_t)rr * K + k0 + cc * 8];
      }
    } else {
      for (int idx = tid; idx < 512; idx += 256) {
        int r = idx >> 3, cc = idx & 7;
        int rr = row0 + r; if (rr >= NNODES) rr = NNODES - 1;
        const unsigned* ap;
        if (k0 < 64)       ap = agg1 + (size_t)rr * 64 + k0 + cc * 8;
        else if (k0 < 192) ap = agg2 + (size_t)rr * 128 + (k0 - 64) + cc * 8;
        else               ap = agg3 + (size_t)rr * 256 + (k0 - 192) + cc * 8;
        f16x8 h;
#pragma unroll
        for (int j = 0; j < 8; ++j) h[j] = dec_f16(ap[j]);
        *(f16x8*)&As[r * SA + cc * 8] = h;
      }
    }
    for (int idx = tid; idx < 1024; idx += 256) {
      int n = idx >> 3, cc = idx & 7;
      *(float4*)&Bs[n * SA + cc * 8] = *(const float4*)&BT[(size_t)(cb0 + n) * K + k0 + cc * 8];
    }
    bar_lgkm();
#pragma unroll
    for (int kh = 0; kh < 2; ++kh) {
      f16x8 af[4], bf[2];
#pragma unroll
      for (int mt = 0; mt < 4; ++mt)
        af[mt] = *(const f16x8*)&As[(mt * 16 + l16) * SA + kh * 32 + quad * 8];
#pragma unroll
      for (int nt = 0; nt < 2; ++nt)
        bf[nt] = *(const f16x8*)&Bs[(wave * 32 + nt * 16 + l16) * SA + kh * 32 + quad * 8];
#pragma unroll
      for (int mt = 0; mt < 4; ++mt)
#pragma unroll
        for (int nt = 0; nt < 2; ++nt)
          acc[mt][nt] = __builtin_amdgcn_mfma_f32_16x16x32_f16(af[mt], bf[nt], acc[mt][nt], 0, 0, 0);
    }
  }
#pragma unroll
  for (int nt = 0; nt < 2; ++nt) {
    int n = cb0 + wave * 32 + nt * 16 + l16;
    float bv = bias[n];
#pragma unroll
    for (int mt = 0; mt < 4; ++mt) {
#pragma unroll
      for (int r = 0; r < 4; ++r) {
        int m = row0 + mt * 16 + quad * 4 + r;
        if (m < NNODES) {
          float v = acc[mt][nt][r] + bv;
          if (RELU) v = fmaxf(v, 0.0f);
          Yv[(size_t)m * NTOT + n] = (_Float16)v;
        }
      }
    }
  }
}

// Final 256 -> 4 projection (f16 input).
__global__ __launch_bounds__(256) void final_kernel(
    const _Float16* __restrict__ X, const float* __restrict__ W,
    const float* __restrict__ b, float* __restrict__ out) {
  __shared__ float as[64][65];
  __shared__ float ws3[256][4];
  __shared__ float bs[4];
  const int tid = threadIdx.x;
  const int row0 = blockIdx.x * 64;
  for (int idx = tid; idx < 256 * 4; idx += 256) ws3[idx >> 2][idx & 3] = W[idx];
  if (tid < 4) bs[tid] = b[tid];
  const int r = tid >> 2, c = tid & 3;
  float acc = 0.0f;
  for (int k0 = 0; k0 < 256; k0 += 64) {
    __syncthreads();
    for (int idx = tid; idx < 512; idx += 256) {  // 64 rows x 64 cols / 8
      int r2 = idx >> 3, cc = idx & 7;
      int rr = row0 + r2; if (rr >= NNODES) rr = NNODES - 1;
      f16x8 v = *(const f16x8*)&X[(size_t)rr * 256 + k0 + cc * 8];
#pragma unroll
      for (int j = 0; j < 8; ++j) as[r2][cc * 8 + j] = (float)v[j];
    }
    __syncthreads();
#pragma unroll
    for (int kk = 0; kk < 64; ++kk) acc = fmaf(as[r][kk], ws3[k0 + kk][c], acc);
  }
  int rr = row0 + r;
  if (rr < NNODES) out[(size_t)rr * 4 + c] = acc + bs[c];
}

extern "C" void kernel_launch(void* const* d_in, const int* in_sizes, int n_in,
                              void* d_out, int out_size, void* d_ws, size_t ws_size,
                              hipStream_t stream) {
  const float* x = (const float*)d_in[0];
  const int* eidx = (const int*)d_in[1];  // int32
  const float* w1a = (const float*)d_in[3];
  const float* b1a = (const float*)d_in[4];
  const float* w1b = (const float*)d_in[5];
  const float* b1b = (const float*)d_in[6];
  const float* w2a = (const float*)d_in[7];
  const float* b2a = (const float*)d_in[8];
  const float* w2b = (const float*)d_in[9];
  const float* b2b = (const float*)d_in[10];
  const float* w3a = (const float*)d_in[11];
  const float* b3a = (const float*)d_in[12];
  const float* w3b = (const float*)d_in[13];
  const float* b3b = (const float*)d_in[14];
  const float* wm1 = (const float*)d_in[15];
  const float* bm1 = (const float*)d_in[16];
  const float* wm2 = (const float*)d_in[17];
  const float* bm2 = (const float*)d_in[18];
  const float* wm3 = (const float*)d_in[19];
  const float* bm3 = (const float*)d_in[20];
  float* out = (float*)d_out;

  // Workspace (halves unless noted), ~87 MB — R6 layout:
  // Ph[N*256] | Qh[N*256] | agg1[N*64 u32] | agg2[N*128 u32] | agg3[N*256 u32]
  //   | sedge[E u32] | wm1h | w2pd/w2pb | w3pd/w3pb
  // Overlays: deg/cur on Ph (dead before pq1); mh1h (f16 N*512) on Ph+Qh
  // (dead after edge3); mh2h (f16 N*256) on agg1+agg2 (dead after mlp1's
  // reads). Edge frag weights + wm2h in d_out (434 KB, read before final).
  _Float16* wsh = (_Float16*)d_ws;
  _Float16* Ph = wsh;
  _Float16* Qh = Ph + (size_t)NNODES * 256;
  unsigned* agg1 = (unsigned*)(Qh + (size_t)NNODES * 256);
  unsigned* agg2 = agg1 + (size_t)NNODES * 64;
  unsigned* agg3 = agg2 + (size_t)NNODES * 128;
  unsigned* sedge = agg3 + (size_t)NNODES * 256;
  _Float16* wm1h = (_Float16*)(sedge + NEDGES);
  _Float16* w2pd = wm1h + 448 * 512;
  _Float16* w2pb = w2pd + 64 * 128;
  _Float16* w3pd = w2pb + 64 * 128;
  _Float16* w3pb = w3pd + 128 * 256;
  int* deg = (int*)Ph;
  int* cur = deg + NNODES;
  _Float16* mh1h = Ph;                     // N*512 halves over Ph+Qh
  _Float16* mh2h = (_Float16*)agg1;        // N*256 halves over agg1+agg2
  _Float16* w1f = (_Float16*)d_out;        // 64*64
  _Float16* w2f = w1f + 4096;              // 128*128
  _Float16* w3f = w2f + 16384;             // 256*256
  _Float16* wm2h = w3f + 65536;            // 256*512 -> total 434 KB

  const int ROWB64 = (NNODES + 63) / 64;     // 469
  const int EB = (NEDGES + 255) / 256;

  // ---- CSR + setup
  fill_u32<<<(NNODES + 255) / 256, 256, 0, stream>>>((unsigned*)deg, NNODES, 0u);
  constexpr int PREP_TOTAL = NNODES * 64 + NEDGES + 448 * 512 + 512 * 256 +
                             64 * 64 + 128 * 128 + 256 * 256 + 64 * 128 + 128 * 256;
  prep_kernel<<<(PREP_TOTAL + 255) / 256, 256, 0, stream>>>(
      eidx, deg, wm1, wm2, w1b, w2b, w3b, w2a, w3a,
      wm1h, wm2h, w1f, w2f, w3f, w2pd, w2pb, w3pd, w3pb, agg1);
  scan_kernel<<<1, 1024, 0, stream>>>(deg, cur);
  scatter_kernel<<<EB, 256, 0, stream>>>(eidx, cur, sedge);

  // ---- EdgeConv 1: C=3 -> 64 (inits agg2: 7500*512 = N*128)
  pq_kernel<3, 64><<<dim3(ROWB64, 1), 256, 0, stream>>>(x, 3, w1a, b1a, Ph, Qh);
  edge_mfma<64, 512><<<NEDGES / 64, 256, 0, stream>>>(sedge, Ph, Qh, w1f, b1b, agg1, agg2);
  // ---- EdgeConv 2: C=64 -> 128 (inits agg3: 7500*1024 = N*256)
  pq_mfma<64, 128><<<dim3(ROWB64, 1), 256, 0, stream>>>(agg1, w2pd, w2pb, b2a, Ph, Qh);
  edge_mfma<128, 1024><<<NEDGES / 64, 256, 0, stream>>>(sedge, Ph, Qh, w2f, b2b, agg2, agg3);
  // ---- EdgeConv 3: C=128 -> 256
  pq_mfma<128, 256><<<dim3(ROWB64, 2), 256, 0, stream>>>(agg2, w3pd, w3pb, b3a, Ph, Qh);
  edge_mfma<256, 0><<<NEDGES / 64, 256, 0, stream>>>(sedge, Ph, Qh, w3f, b3b, agg3, nullptr);
  // ---- MLP head: mlp1 inline-decode; mlp2 separate; final
  mlp_mfma<448, 512, true, true><<<dim3(ROWB64, 4), 256, 0, stream>>>(
      nullptr, agg1, agg2, agg3, wm1h, bm1, mh1h);
  mlp_mfma<512, 256, true, false><<<dim3(ROWB64, 2), 256, 0, stream>>>(
      mh1h, nullptr, nullptr, nullptr, wm2h, bm2, mh2h);
  final_kernel<<<ROWB64, 256, 0, stream>>>(mh2h, wm3, bm3, out);
}